// Round 6
// baseline (376.326 us; speedup 1.0000x reference)
//
#include <hip/hip_runtime.h>
#include <hip/hip_bf16.h>
#include <math.h>

// ChannelMambaBlock fused — Round 6: barrier-free wave-private pixels, spill-free
// B=4, C=192, H=128, W=128, K=4, DSTATE=8, DTRANK=12
// Block = 4 waves; EACH WAVE privately owns 16 consecutive-W pixels end-to-end.
// grid = 1024 blocks = exactly 4 blocks/CU. ZERO __syncthreads.
// vs R5 (which spilled: peak ~130 live VGPRs > 128 cap -> 450MB scratch traffic):
// yp[12][2] eliminated — y is written in-place into mX during the dt phase and
// LN2 stats (sum/sumsq) are accumulated on the fly (8 regs, not 24). LN2 then
// shfl-reduces within each 16-lane quarter and normalizes from LDS.

#define CC    192
#define HH    128
#define WW    128
#define NK    4
#define DST   8
#define DTR   12
#define NTH   256
#define SP    200         // sX row stride (400B: 16B-aligned rows)
#define SD    112         // sXD row stride (224B: 16B-aligned rows)

typedef __attribute__((ext_vector_type(8))) short bh8;   // 8 bf16 = 4 VGPR
typedef __attribute__((ext_vector_type(4))) float f4;

// bf16 weight segments inside d_ws (ushort elems)
#define OFF_WIN    0
#define OFF_SSMIN  73728        // 384*192
#define OFF_XPROJ  147456
#define OFF_SSMOUT 168960       // + 112*192
#define OFF_WOUT   205824
#define OFF_DTW    242688       // + 192*192  -> B_dt [k][c][32]
#define WTOT2      267264       // + 4*192*32
// f32 Dsum[192] at ushort offset WTOT2

#define MFMA(va, vb, vc) __builtin_amdgcn_mfma_f32_16x16x32_bf16(va, vb, vc, 0, 0, 0)

__device__ __forceinline__ float bf2f(unsigned short u) {
    union { unsigned int i; float f; } v; v.i = ((unsigned int)u) << 16; return v.f;
}
__device__ __forceinline__ unsigned short f2bf(float f) {
    __hip_bfloat16 h = __float2bfloat16(f);
    unsigned short u; __builtin_memcpy(&u, &h, 2); return u;
}
__device__ __forceinline__ unsigned int pk2(float a, float b) {
    return (unsigned int)f2bf(a) | ((unsigned int)f2bf(b) << 16);
}
__device__ __forceinline__ float lo16(unsigned int u) { return bf2f((unsigned short)(u & 0xffffu)); }
__device__ __forceinline__ float hi16(unsigned int u) { return bf2f((unsigned short)(u >> 16)); }

#define LOG2E 1.44269504f
#define LN2C  0.69314718f
__device__ __forceinline__ float silu_fast(float x) {
    float e = __builtin_amdgcn_exp2f(-LOG2E * x);
    return x * __builtin_amdgcn_rcpf(1.f + e);
}
__device__ __forceinline__ float softplus_fast(float x) {
    float e = __builtin_amdgcn_exp2f(-LOG2E * fabsf(x));
    return fmaxf(x, 0.f) + LN2C * __builtin_amdgcn_logf(1.f + e);
}

extern "C" __global__ void prep_w(const float* __restrict__ w_in,
                                  const float* __restrict__ ssm_in_w,
                                  const float* __restrict__ x_proj_w,
                                  const float* __restrict__ ssm_out_w,
                                  const float* __restrict__ w_out,
                                  const float* __restrict__ dt_w,
                                  const float* __restrict__ dt_b,
                                  const float* __restrict__ Ds,
                                  unsigned short* __restrict__ wb)
{
    int i = blockIdx.x * NTH + threadIdx.x;
    if (i < OFF_DTW) {
        float v;
        if      (i < OFF_XPROJ ) v = (i < OFF_SSMIN) ? w_in[i] : ssm_in_w[i - OFF_SSMIN];
        else if (i < OFF_SSMOUT) v = x_proj_w[i - OFF_XPROJ];
        else if (i < OFF_WOUT  ) v = ssm_out_w[i - OFF_SSMOUT];
        else                     v = w_out[i - OFF_WOUT];
        wb[i] = f2bf(v);
    } else if (i < WTOT2) {
        int j  = i - OFF_DTW;
        int r  = j & 31;
        int kc = j >> 5;
        float v = (r < DTR) ? dt_w[kc * DTR + r]
                            : (r == 31 ? dt_b[kc] : 0.f);
        wb[i] = f2bf(v);
    } else if (i < WTOT2 + CC) {
        int c = i - WTOT2;
        float* dsum = (float*)(wb + WTOT2);
        dsum[c] = Ds[c] + Ds[CC + c] + Ds[2*CC + c] + Ds[3*CC + c];
    }
}

template<int NT>
__device__ __forceinline__ void gemmN(const bh8 a[6], const unsigned short* wp,
                                      f4 acc[NT]) {
#pragma unroll
    for (int ks = 0; ks < 6; ++ks)
#pragma unroll
        for (int j = 0; j < NT; ++j) {
            bh8 bf = *(const bh8*)(wp + (size_t)j * 16 * CC + ks * 32);
            acc[j] = MFMA(a[ks], bf, acc[j]);
        }
}

extern "C" __global__ void __launch_bounds__(NTH, 4)
mamba_fused(const float* __restrict__ x,
            const float* __restrict__ norm_w,  const float* __restrict__ norm_b,
            const float* __restrict__ out_norm_w, const float* __restrict__ out_norm_b,
            const unsigned short* __restrict__ wsb,
            float* __restrict__ out)
{
    __shared__ __align__(16) unsigned short sX [4][16][SP];   // 25600 B
    __shared__ __align__(16) unsigned short sXD[4][16][SD];   // 14336 B
    __shared__ __align__(16) float sbc[4][NK][16];            //  1024 B => 40960 B

    const int tid  = threadIdx.x;
    const int lane = tid & 63;
    const int wv   = tid >> 6;
    const int frow = lane & 15;
    const int kb   = lane >> 4;
    const int pxb  = kb * 4;

    const int t   = blockIdx.x;          // 1024 blocks
    const int b   = t >> 8;
    const int rem = t & 255;
    const int h   = rem >> 1;
    const int w0  = (rem & 1) * 64 + wv * 16;   // wave's first pixel (w coord)

    unsigned short (*mX)[SP]  = sX[wv];
    unsigned short (*mXD)[SD] = sXD[wv];
    float (*mbc)[16]          = sbc[wv];

    const float* dsum = (const float*)(wsb + WTOT2);

    // persistent packed-bf16 registers (D-layout: tile j <-> chan j*16+frow,
    // rows pxb..pxb+3): x2p = silu(x2), zp = silu(z).  (yp removed vs R5.)
    unsigned int x2p[12][2], zp[12][2];

    // ---------------- LN1: load x, normalize -> mX = xn (bf16) ------------------
    {
        const int c0 = kb * 48;
        const size_t base = (((size_t)b * CC + c0) * HH + h) * WW + w0 + frow;
        float v[48];
        float sum = 0.f, sq = 0.f;
#pragma unroll
        for (int i = 0; i < 48; ++i) {
            v[i] = x[base + (size_t)i * (HH * WW)];
            sum += v[i]; sq += v[i] * v[i];
        }
        sum += __shfl_xor(sum, 16); sum += __shfl_xor(sum, 32);
        sq  += __shfl_xor(sq , 16); sq  += __shfl_xor(sq , 32);
        float mu = sum * (1.f / CC);
        float rs = rsqrtf(sq * (1.f / CC) - mu * mu + 1e-5f);
#pragma unroll
        for (int i = 0; i < 48; ++i) {
            int c = c0 + i;
            mX[frow][c] = f2bf((v[i] - mu) * rs * norm_w[c] + norm_b[c]);
        }
    }

    bh8 a[6];
    auto load_a = [&]() {
#pragma unroll
        for (int ks = 0; ks < 6; ++ks)
            a[ks] = *(const bh8*)(&mX[frow][ks * 32 + kb * 8]);
    };

    // ---------------- GEMM1: p = xn @ w_in^T -> mX = x1, x2p = silu(x2) ---------
    {
        load_a();
        const unsigned short* wB = wsb + OFF_WIN;
#pragma unroll
        for (int g = 0; g < 6; ++g) {
            f4 acc[4] = {{0,0,0,0},{0,0,0,0},{0,0,0,0},{0,0,0,0}};
            gemmN<4>(a, wB + (size_t)(g * 64 + frow) * CC + kb * 8, acc);
#pragma unroll
            for (int j = 0; j < 4; ++j) {
                int tile = g * 4 + j;
                int o = tile * 16 + frow;
                if (tile < 12) {
#pragma unroll
                    for (int r = 0; r < 4; ++r) mX[pxb + r][o] = f2bf(acc[j][r]);
                } else {
                    x2p[tile - 12][0] = pk2(silu_fast(acc[j][0]), silu_fast(acc[j][1]));
                    x2p[tile - 12][1] = pk2(silu_fast(acc[j][2]), silu_fast(acc[j][3]));
                }
            }
        }
    }

    // ---------------- GEMM2: u = x1 @ ssm_in^T -> mX = silu(xss), zp = silu(z) --
    {
        load_a();                       // x1
        const unsigned short* wB = wsb + OFF_SSMIN;
#pragma unroll
        for (int g = 0; g < 6; ++g) {
            f4 acc[4] = {{0,0,0,0},{0,0,0,0},{0,0,0,0},{0,0,0,0}};
            gemmN<4>(a, wB + (size_t)(g * 64 + frow) * CC + kb * 8, acc);
#pragma unroll
            for (int j = 0; j < 4; ++j) {
                int tile = g * 4 + j;
                int o = tile * 16 + frow;
                if (tile < 12) {
#pragma unroll
                    for (int r = 0; r < 4; ++r)
                        mX[pxb + r][o] = f2bf(silu_fast(acc[j][r]));
                } else {
                    zp[tile - 12][0] = pk2(silu_fast(acc[j][0]), silu_fast(acc[j][1]));
                    zp[tile - 12][1] = pk2(silu_fast(acc[j][2]), silu_fast(acc[j][3]));
                }
            }
        }
    }

    // ---------------- GEMM3: xd = xss @ x_proj^T (112) -> mXD -------------------
    {
        load_a();                       // silu(xss)
        const unsigned short* wB = wsb + OFF_XPROJ;
        {
            f4 acc[4] = {{0,0,0,0},{0,0,0,0},{0,0,0,0},{0,0,0,0}};
            gemmN<4>(a, wB + (size_t)frow * CC + kb * 8, acc);
#pragma unroll
            for (int j = 0; j < 4; ++j) {
                int o = j * 16 + frow;
#pragma unroll
                for (int r = 0; r < 4; ++r) mXD[pxb + r][o] = f2bf(acc[j][r]);
            }
        }
        {
            f4 acc[3] = {{0,0,0,0},{0,0,0,0},{0,0,0,0}};
            gemmN<3>(a, wB + (size_t)(64 + frow) * CC + kb * 8, acc);
#pragma unroll
            for (int j = 0; j < 3; ++j) {
                int o = (4 + j) * 16 + frow;
#pragma unroll
                for (int r = 0; r < 4; ++r) mXD[pxb + r][o] = f2bf(acc[j][r]);
            }
        }
    }

    // ---------------- bc[k][px] = dot(Bv, Cv) -----------------------------------
    {
        const unsigned short* rp = &mXD[frow][kb * 28 + DTR];
        float acc = 0.f;
#pragma unroll
        for (int s = 0; s < DST; ++s)
            acc += bf2f(rp[s]) * bf2f(rp[DST + s]);
        mbc[kb][frow] = acc;
    }

    // ---------------- dt-MFMA: y = xss*(sum_k bc*softplus(.) + Dsum) ------------
    // y written IN-PLACE into mX; LN2 stats accumulated on the fly (no yp regs).
    f4 l2sum = {0.f,0.f,0.f,0.f}, l2sq = {0.f,0.f,0.f,0.f};
    {
        bh8 adt[NK];
#pragma unroll
        for (int k = 0; k < NK; ++k) {
            const unsigned short* rp = &mXD[frow][k * 28];
            bh8 vv;
            if (kb == 0) {
                ushort4 lo = *(const ushort4*)(rp);
                ushort4 hi = *(const ushort4*)(rp + 4);
                vv = bh8{(short)lo.x,(short)lo.y,(short)lo.z,(short)lo.w,
                         (short)hi.x,(short)hi.y,(short)hi.z,(short)hi.w};
            } else if (kb == 1) {
                ushort4 lo = *(const ushort4*)(rp + 8);
                vv = bh8{(short)lo.x,(short)lo.y,(short)lo.z,(short)lo.w,0,0,0,0};
            } else if (kb == 2) {
                vv = bh8{0,0,0,0,0,0,0,0};
            } else {
                vv = bh8{0,0,0,0,0,0,0,(short)0x3F80};   // bf16 1.0 -> col 31 (dt_b)
            }
            adt[k] = vv;
        }
        f4 bck[NK];
#pragma unroll
        for (int k = 0; k < NK; ++k) bck[k] = *(const f4*)(&mbc[k][pxb]);

        const unsigned short* wDT = wsb + OFF_DTW;
#pragma unroll
        for (int ct = 0; ct < 12; ++ct) {
            int c = ct * 16 + frow;
            f4 g = {0.f,0.f,0.f,0.f};
#pragma unroll
            for (int k = 0; k < NK; ++k) {
                bh8 bf = *(const bh8*)(wDT + (((size_t)(k * CC + c)) << 5) + kb * 8);
                f4 d = {0.f,0.f,0.f,0.f};
                d = MFMA(adt[k], bf, d);
#pragma unroll
                for (int r = 0; r < 4; ++r)
                    g[r] += bck[k][r] * softplus_fast(d[r]);
            }
            float ds = dsum[c];
#pragma unroll
            for (int r = 0; r < 4; ++r) {
                float yv = bf2f(mX[pxb + r][c]) * (g[r] + ds);
                mX[pxb + r][c] = f2bf(yv);            // in-place: xss slot -> y
                l2sum[r] += yv; l2sq[r] += yv * yv;
            }
        }
    }

    // ---------------- LN2 over y (per pixel), * z -> mX = yz --------------------
    // Pixel pxb+r's channels live only across frow lanes -> reduce masks 1,2,4,8.
    {
#pragma unroll
        for (int m = 1; m < 16; m <<= 1) {
#pragma unroll
            for (int r = 0; r < 4; ++r) {
                l2sum[r] += __shfl_xor(l2sum[r], m);
                l2sq[r]  += __shfl_xor(l2sq[r],  m);
            }
        }
        f4 mu, rs;
#pragma unroll
        for (int r = 0; r < 4; ++r) {
            mu[r] = l2sum[r] * (1.f / CC);
            rs[r] = rsqrtf(l2sq[r] * (1.f / CC) - mu[r] * mu[r] + 1e-5f);
        }
#pragma unroll
        for (int ct = 0; ct < 12; ++ct) {
            int c = ct * 16 + frow;
            float wn = out_norm_w[c], bn = out_norm_b[c];
            float z0 = lo16(zp[ct][0]), z1 = hi16(zp[ct][0]);
            float z2 = lo16(zp[ct][1]), z3 = hi16(zp[ct][1]);
            float y0 = bf2f(mX[pxb + 0][c]);
            float y1 = bf2f(mX[pxb + 1][c]);
            float y2 = bf2f(mX[pxb + 2][c]);
            float y3 = bf2f(mX[pxb + 3][c]);
            mX[pxb + 0][c] = f2bf(((y0 - mu[0]) * rs[0] * wn + bn) * z0);
            mX[pxb + 1][c] = f2bf(((y1 - mu[1]) * rs[1] * wn + bn) * z1);
            mX[pxb + 2][c] = f2bf(((y2 - mu[2]) * rs[2] * wn + bn) * z2);
            mX[pxb + 3][c] = f2bf(((y3 - mu[3]) * rs[3] * wn + bn) * z3);
        }
    }

    // ---------------- GEMM4: s = yz @ ssm_out^T; mX = s * silu(x2) --------------
    {
        load_a();                       // yz
        const unsigned short* wB = wsb + OFF_SSMOUT;
#pragma unroll
        for (int g = 0; g < 3; ++g) {
            f4 acc[4] = {{0,0,0,0},{0,0,0,0},{0,0,0,0},{0,0,0,0}};
            gemmN<4>(a, wB + (size_t)(g * 64 + frow) * CC + kb * 8, acc);
#pragma unroll
            for (int j = 0; j < 4; ++j) {
                int tile = g * 4 + j;
                int o = tile * 16 + frow;
                mX[pxb + 0][o] = f2bf(acc[j][0] * lo16(x2p[tile][0]));
                mX[pxb + 1][o] = f2bf(acc[j][1] * hi16(x2p[tile][0]));
                mX[pxb + 2][o] = f2bf(acc[j][2] * lo16(x2p[tile][1]));
                mX[pxb + 3][o] = f2bf(acc[j][3] * hi16(x2p[tile][1]));
            }
        }
    }

    // ---------------- GEMM5: o = (s*x2) @ w_out^T; out = x + o ------------------
    {
        load_a();                       // s*x2
        const unsigned short* wB = wsb + OFF_WOUT;
#pragma unroll
        for (int g = 0; g < 3; ++g) {
            f4 acc[4] = {{0,0,0,0},{0,0,0,0},{0,0,0,0},{0,0,0,0}};
            gemmN<4>(a, wB + (size_t)(g * 64 + frow) * CC + kb * 8, acc);
#pragma unroll
            for (int j = 0; j < 4; ++j) {
                int o = (g * 4 + j) * 16 + frow;
                const size_t g0 = (((size_t)b * CC + o) * HH + h) * WW + w0 + pxb;
                float4 xv = *(const float4*)(x + g0);
                float4 ov;
                ov.x = xv.x + acc[j][0];
                ov.y = xv.y + acc[j][1];
                ov.z = xv.z + acc[j][2];
                ov.w = xv.w + acc[j][3];
                *(float4*)(out + g0) = ov;
            }
        }
    }
}

extern "C" void kernel_launch(void* const* d_in, const int* in_sizes, int n_in,
                              void* d_out, int out_size, void* d_ws, size_t ws_size,
                              hipStream_t stream) {
    const float* x          = (const float*)d_in[0];
    const float* norm_w     = (const float*)d_in[1];
    const float* norm_b     = (const float*)d_in[2];
    const float* w_in       = (const float*)d_in[3];
    const float* ssm_in_w   = (const float*)d_in[4];
    const float* x_proj_w   = (const float*)d_in[5];
    const float* dt_w       = (const float*)d_in[6];
    const float* dt_b       = (const float*)d_in[7];
    // d_in[8] = A_logs : unused by the reference computation
    const float* Ds         = (const float*)d_in[9];
    const float* out_norm_w = (const float*)d_in[10];
    const float* out_norm_b = (const float*)d_in[11];
    const float* ssm_out_w  = (const float*)d_in[12];
    const float* w_out      = (const float*)d_in[13];

    unsigned short* wb = (unsigned short*)d_ws;
    int prep_n = WTOT2 + CC;
    prep_w<<<dim3((prep_n + NTH - 1) / NTH), dim3(NTH), 0, stream>>>(
        w_in, ssm_in_w, x_proj_w, ssm_out_w, w_out, dt_w, dt_b, Ds, wb);

    mamba_fused<<<dim3(1024), dim3(NTH), 0, stream>>>(
        x, norm_w, norm_b, out_norm_w, out_norm_b, wb, (float*)d_out);
}

// Round 7
// 375.662 us; speedup vs baseline: 1.0018x; 1.0018x over previous
//
#include <hip/hip_runtime.h>
#include <hip/hip_bf16.h>
#include <math.h>

// ChannelMambaBlock fused — Round 7: R6 structure + pinned 4 waves/EU (128 VGPR)
// B=4, C=192, H=128, W=128, K=4, DSTATE=8, DTRANK=12
// Block = 4 waves; EACH WAVE privately owns 16 consecutive-W pixels end-to-end.
// grid = 1024 blocks = exactly 4 blocks/CU. ZERO __syncthreads.
// vs R6: the ONLY change is amdgpu_waves_per_eu(4,4) replacing launch_bounds'
// min-waves arg. R4-R6 all compiled to a 64-VGPR allocation (8-waves/SIMD
// bucket) even though 40KB LDS caps occupancy at 4 waves/SIMD — so ~100 live
// values spilled to scratch (=> 330MB excess HBM WRITE, 70MB excess FETCH).
// Pinning waves/EU=4 raises the budget to 128 VGPRs; peak live ~110 fits.

#define CC    192
#define HH    128
#define WW    128
#define NK    4
#define DST   8
#define DTR   12
#define NTH   256
#define SP    200         // sX row stride (400B: 16B-aligned rows)
#define SD    112         // sXD row stride (224B: 16B-aligned rows)

typedef __attribute__((ext_vector_type(8))) short bh8;   // 8 bf16 = 4 VGPR
typedef __attribute__((ext_vector_type(4))) float f4;

// bf16 weight segments inside d_ws (ushort elems)
#define OFF_WIN    0
#define OFF_SSMIN  73728        // 384*192
#define OFF_XPROJ  147456
#define OFF_SSMOUT 168960       // + 112*192
#define OFF_WOUT   205824
#define OFF_DTW    242688       // + 192*192  -> B_dt [k][c][32]
#define WTOT2      267264       // + 4*192*32
// f32 Dsum[192] at ushort offset WTOT2

#define MFMA(va, vb, vc) __builtin_amdgcn_mfma_f32_16x16x32_bf16(va, vb, vc, 0, 0, 0)

__device__ __forceinline__ float bf2f(unsigned short u) {
    union { unsigned int i; float f; } v; v.i = ((unsigned int)u) << 16; return v.f;
}
__device__ __forceinline__ unsigned short f2bf(float f) {
    __hip_bfloat16 h = __float2bfloat16(f);
    unsigned short u; __builtin_memcpy(&u, &h, 2); return u;
}
__device__ __forceinline__ unsigned int pk2(float a, float b) {
    return (unsigned int)f2bf(a) | ((unsigned int)f2bf(b) << 16);
}
__device__ __forceinline__ float lo16(unsigned int u) { return bf2f((unsigned short)(u & 0xffffu)); }
__device__ __forceinline__ float hi16(unsigned int u) { return bf2f((unsigned short)(u >> 16)); }

#define LOG2E 1.44269504f
#define LN2C  0.69314718f
__device__ __forceinline__ float silu_fast(float x) {
    float e = __builtin_amdgcn_exp2f(-LOG2E * x);
    return x * __builtin_amdgcn_rcpf(1.f + e);
}
__device__ __forceinline__ float softplus_fast(float x) {
    float e = __builtin_amdgcn_exp2f(-LOG2E * fabsf(x));
    return fmaxf(x, 0.f) + LN2C * __builtin_amdgcn_logf(1.f + e);
}

extern "C" __global__ void prep_w(const float* __restrict__ w_in,
                                  const float* __restrict__ ssm_in_w,
                                  const float* __restrict__ x_proj_w,
                                  const float* __restrict__ ssm_out_w,
                                  const float* __restrict__ w_out,
                                  const float* __restrict__ dt_w,
                                  const float* __restrict__ dt_b,
                                  const float* __restrict__ Ds,
                                  unsigned short* __restrict__ wb)
{
    int i = blockIdx.x * NTH + threadIdx.x;
    if (i < OFF_DTW) {
        float v;
        if      (i < OFF_XPROJ ) v = (i < OFF_SSMIN) ? w_in[i] : ssm_in_w[i - OFF_SSMIN];
        else if (i < OFF_SSMOUT) v = x_proj_w[i - OFF_XPROJ];
        else if (i < OFF_WOUT  ) v = ssm_out_w[i - OFF_SSMOUT];
        else                     v = w_out[i - OFF_WOUT];
        wb[i] = f2bf(v);
    } else if (i < WTOT2) {
        int j  = i - OFF_DTW;
        int r  = j & 31;
        int kc = j >> 5;
        float v = (r < DTR) ? dt_w[kc * DTR + r]
                            : (r == 31 ? dt_b[kc] : 0.f);
        wb[i] = f2bf(v);
    } else if (i < WTOT2 + CC) {
        int c = i - WTOT2;
        float* dsum = (float*)(wb + WTOT2);
        dsum[c] = Ds[c] + Ds[CC + c] + Ds[2*CC + c] + Ds[3*CC + c];
    }
}

template<int NT>
__device__ __forceinline__ void gemmN(const bh8 a[6], const unsigned short* wp,
                                      f4 acc[NT]) {
#pragma unroll
    for (int ks = 0; ks < 6; ++ks)
#pragma unroll
        for (int j = 0; j < NT; ++j) {
            bh8 bf = *(const bh8*)(wp + (size_t)j * 16 * CC + ks * 32);
            acc[j] = MFMA(a[ks], bf, acc[j]);
        }
}

extern "C" __global__ void __launch_bounds__(NTH)
__attribute__((amdgpu_waves_per_eu(4, 4)))
mamba_fused(const float* __restrict__ x,
            const float* __restrict__ norm_w,  const float* __restrict__ norm_b,
            const float* __restrict__ out_norm_w, const float* __restrict__ out_norm_b,
            const unsigned short* __restrict__ wsb,
            float* __restrict__ out)
{
    __shared__ __align__(16) unsigned short sX [4][16][SP];   // 25600 B
    __shared__ __align__(16) unsigned short sXD[4][16][SD];   // 14336 B
    __shared__ __align__(16) float sbc[4][NK][16];            //  1024 B => 40960 B

    const int tid  = threadIdx.x;
    const int lane = tid & 63;
    const int wv   = tid >> 6;
    const int frow = lane & 15;
    const int kb   = lane >> 4;
    const int pxb  = kb * 4;

    const int t   = blockIdx.x;          // 1024 blocks
    const int b   = t >> 8;
    const int rem = t & 255;
    const int h   = rem >> 1;
    const int w0  = (rem & 1) * 64 + wv * 16;   // wave's first pixel (w coord)

    unsigned short (*mX)[SP]  = sX[wv];
    unsigned short (*mXD)[SD] = sXD[wv];
    float (*mbc)[16]          = sbc[wv];

    const float* dsum = (const float*)(wsb + WTOT2);

    // persistent packed-bf16 registers (D-layout: tile j <-> chan j*16+frow,
    // rows pxb..pxb+3): x2p = silu(x2), zp = silu(z).
    unsigned int x2p[12][2], zp[12][2];

    // ---------------- LN1: load x, normalize -> mX = xn (bf16) ------------------
    {
        const int c0 = kb * 48;
        const size_t base = (((size_t)b * CC + c0) * HH + h) * WW + w0 + frow;
        float v[48];
        float sum = 0.f, sq = 0.f;
#pragma unroll
        for (int i = 0; i < 48; ++i) {
            v[i] = x[base + (size_t)i * (HH * WW)];
            sum += v[i]; sq += v[i] * v[i];
        }
        sum += __shfl_xor(sum, 16); sum += __shfl_xor(sum, 32);
        sq  += __shfl_xor(sq , 16); sq  += __shfl_xor(sq , 32);
        float mu = sum * (1.f / CC);
        float rs = rsqrtf(sq * (1.f / CC) - mu * mu + 1e-5f);
#pragma unroll
        for (int i = 0; i < 48; ++i) {
            int c = c0 + i;
            mX[frow][c] = f2bf((v[i] - mu) * rs * norm_w[c] + norm_b[c]);
        }
    }

    bh8 a[6];
    auto load_a = [&]() {
#pragma unroll
        for (int ks = 0; ks < 6; ++ks)
            a[ks] = *(const bh8*)(&mX[frow][ks * 32 + kb * 8]);
    };

    // ---------------- GEMM1: p = xn @ w_in^T -> mX = x1, x2p = silu(x2) ---------
    {
        load_a();
        const unsigned short* wB = wsb + OFF_WIN;
#pragma unroll
        for (int g = 0; g < 6; ++g) {
            f4 acc[4] = {{0,0,0,0},{0,0,0,0},{0,0,0,0},{0,0,0,0}};
            gemmN<4>(a, wB + (size_t)(g * 64 + frow) * CC + kb * 8, acc);
#pragma unroll
            for (int j = 0; j < 4; ++j) {
                int tile = g * 4 + j;
                int o = tile * 16 + frow;
                if (tile < 12) {
#pragma unroll
                    for (int r = 0; r < 4; ++r) mX[pxb + r][o] = f2bf(acc[j][r]);
                } else {
                    x2p[tile - 12][0] = pk2(silu_fast(acc[j][0]), silu_fast(acc[j][1]));
                    x2p[tile - 12][1] = pk2(silu_fast(acc[j][2]), silu_fast(acc[j][3]));
                }
            }
        }
    }

    // ---------------- GEMM2: u = x1 @ ssm_in^T -> mX = silu(xss), zp = silu(z) --
    {
        load_a();                       // x1
        const unsigned short* wB = wsb + OFF_SSMIN;
#pragma unroll
        for (int g = 0; g < 6; ++g) {
            f4 acc[4] = {{0,0,0,0},{0,0,0,0},{0,0,0,0},{0,0,0,0}};
            gemmN<4>(a, wB + (size_t)(g * 64 + frow) * CC + kb * 8, acc);
#pragma unroll
            for (int j = 0; j < 4; ++j) {
                int tile = g * 4 + j;
                int o = tile * 16 + frow;
                if (tile < 12) {
#pragma unroll
                    for (int r = 0; r < 4; ++r)
                        mX[pxb + r][o] = f2bf(silu_fast(acc[j][r]));
                } else {
                    zp[tile - 12][0] = pk2(silu_fast(acc[j][0]), silu_fast(acc[j][1]));
                    zp[tile - 12][1] = pk2(silu_fast(acc[j][2]), silu_fast(acc[j][3]));
                }
            }
        }
    }

    // ---------------- GEMM3: xd = xss @ x_proj^T (112) -> mXD -------------------
    {
        load_a();                       // silu(xss)
        const unsigned short* wB = wsb + OFF_XPROJ;
        {
            f4 acc[4] = {{0,0,0,0},{0,0,0,0},{0,0,0,0},{0,0,0,0}};
            gemmN<4>(a, wB + (size_t)frow * CC + kb * 8, acc);
#pragma unroll
            for (int j = 0; j < 4; ++j) {
                int o = j * 16 + frow;
#pragma unroll
                for (int r = 0; r < 4; ++r) mXD[pxb + r][o] = f2bf(acc[j][r]);
            }
        }
        {
            f4 acc[3] = {{0,0,0,0},{0,0,0,0},{0,0,0,0}};
            gemmN<3>(a, wB + (size_t)(64 + frow) * CC + kb * 8, acc);
#pragma unroll
            for (int j = 0; j < 3; ++j) {
                int o = (4 + j) * 16 + frow;
#pragma unroll
                for (int r = 0; r < 4; ++r) mXD[pxb + r][o] = f2bf(acc[j][r]);
            }
        }
    }

    // ---------------- bc[k][px] = dot(Bv, Cv) -----------------------------------
    {
        const unsigned short* rp = &mXD[frow][kb * 28 + DTR];
        float acc = 0.f;
#pragma unroll
        for (int s = 0; s < DST; ++s)
            acc += bf2f(rp[s]) * bf2f(rp[DST + s]);
        mbc[kb][frow] = acc;
    }

    // ---------------- dt-MFMA: y = xss*(sum_k bc*softplus(.) + Dsum) ------------
    // y written IN-PLACE into mX; LN2 stats accumulated on the fly.
    f4 l2sum = {0.f,0.f,0.f,0.f}, l2sq = {0.f,0.f,0.f,0.f};
    {
        bh8 adt[NK];
#pragma unroll
        for (int k = 0; k < NK; ++k) {
            const unsigned short* rp = &mXD[frow][k * 28];
            bh8 vv;
            if (kb == 0) {
                ushort4 lo = *(const ushort4*)(rp);
                ushort4 hi = *(const ushort4*)(rp + 4);
                vv = bh8{(short)lo.x,(short)lo.y,(short)lo.z,(short)lo.w,
                         (short)hi.x,(short)hi.y,(short)hi.z,(short)hi.w};
            } else if (kb == 1) {
                ushort4 lo = *(const ushort4*)(rp + 8);
                vv = bh8{(short)lo.x,(short)lo.y,(short)lo.z,(short)lo.w,0,0,0,0};
            } else if (kb == 2) {
                vv = bh8{0,0,0,0,0,0,0,0};
            } else {
                vv = bh8{0,0,0,0,0,0,0,(short)0x3F80};   // bf16 1.0 -> col 31 (dt_b)
            }
            adt[k] = vv;
        }
        f4 bck[NK];
#pragma unroll
        for (int k = 0; k < NK; ++k) bck[k] = *(const f4*)(&mbc[k][pxb]);

        const unsigned short* wDT = wsb + OFF_DTW;
#pragma unroll
        for (int ct = 0; ct < 12; ++ct) {
            int c = ct * 16 + frow;
            f4 g = {0.f,0.f,0.f,0.f};
#pragma unroll
            for (int k = 0; k < NK; ++k) {
                bh8 bf = *(const bh8*)(wDT + (((size_t)(k * CC + c)) << 5) + kb * 8);
                f4 d = {0.f,0.f,0.f,0.f};
                d = MFMA(adt[k], bf, d);
#pragma unroll
                for (int r = 0; r < 4; ++r)
                    g[r] += bck[k][r] * softplus_fast(d[r]);
            }
            float ds = dsum[c];
#pragma unroll
            for (int r = 0; r < 4; ++r) {
                float yv = bf2f(mX[pxb + r][c]) * (g[r] + ds);
                mX[pxb + r][c] = f2bf(yv);            // in-place: xss slot -> y
                l2sum[r] += yv; l2sq[r] += yv * yv;
            }
        }
    }

    // ---------------- LN2 over y (per pixel), * z -> mX = yz --------------------
    {
#pragma unroll
        for (int m = 1; m < 16; m <<= 1) {
#pragma unroll
            for (int r = 0; r < 4; ++r) {
                l2sum[r] += __shfl_xor(l2sum[r], m);
                l2sq[r]  += __shfl_xor(l2sq[r],  m);
            }
        }
        f4 mu, rs;
#pragma unroll
        for (int r = 0; r < 4; ++r) {
            mu[r] = l2sum[r] * (1.f / CC);
            rs[r] = rsqrtf(l2sq[r] * (1.f / CC) - mu[r] * mu[r] + 1e-5f);
        }
#pragma unroll
        for (int ct = 0; ct < 12; ++ct) {
            int c = ct * 16 + frow;
            float wn = out_norm_w[c], bn = out_norm_b[c];
            float z0 = lo16(zp[ct][0]), z1 = hi16(zp[ct][0]);
            float z2 = lo16(zp[ct][1]), z3 = hi16(zp[ct][1]);
            float y0 = bf2f(mX[pxb + 0][c]);
            float y1 = bf2f(mX[pxb + 1][c]);
            float y2 = bf2f(mX[pxb + 2][c]);
            float y3 = bf2f(mX[pxb + 3][c]);
            mX[pxb + 0][c] = f2bf(((y0 - mu[0]) * rs[0] * wn + bn) * z0);
            mX[pxb + 1][c] = f2bf(((y1 - mu[1]) * rs[1] * wn + bn) * z1);
            mX[pxb + 2][c] = f2bf(((y2 - mu[2]) * rs[2] * wn + bn) * z2);
            mX[pxb + 3][c] = f2bf(((y3 - mu[3]) * rs[3] * wn + bn) * z3);
        }
    }

    // ---------------- GEMM4: s = yz @ ssm_out^T; mX = s * silu(x2) --------------
    {
        load_a();                       // yz
        const unsigned short* wB = wsb + OFF_SSMOUT;
#pragma unroll
        for (int g = 0; g < 3; ++g) {
            f4 acc[4] = {{0,0,0,0},{0,0,0,0},{0,0,0,0},{0,0,0,0}};
            gemmN<4>(a, wB + (size_t)(g * 64 + frow) * CC + kb * 8, acc);
#pragma unroll
            for (int j = 0; j < 4; ++j) {
                int tile = g * 4 + j;
                int o = tile * 16 + frow;
                mX[pxb + 0][o] = f2bf(acc[j][0] * lo16(x2p[tile][0]));
                mX[pxb + 1][o] = f2bf(acc[j][1] * hi16(x2p[tile][0]));
                mX[pxb + 2][o] = f2bf(acc[j][2] * lo16(x2p[tile][1]));
                mX[pxb + 3][o] = f2bf(acc[j][3] * hi16(x2p[tile][1]));
            }
        }
    }

    // ---------------- GEMM5: o = (s*x2) @ w_out^T; out = x + o ------------------
    {
        load_a();                       // s*x2
        const unsigned short* wB = wsb + OFF_WOUT;
#pragma unroll
        for (int g = 0; g < 3; ++g) {
            f4 acc[4] = {{0,0,0,0},{0,0,0,0},{0,0,0,0},{0,0,0,0}};
            gemmN<4>(a, wB + (size_t)(g * 64 + frow) * CC + kb * 8, acc);
#pragma unroll
            for (int j = 0; j < 4; ++j) {
                int o = (g * 4 + j) * 16 + frow;
                const size_t g0 = (((size_t)b * CC + o) * HH + h) * WW + w0 + pxb;
                float4 xv = *(const float4*)(x + g0);
                float4 ov;
                ov.x = xv.x + acc[j][0];
                ov.y = xv.y + acc[j][1];
                ov.z = xv.z + acc[j][2];
                ov.w = xv.w + acc[j][3];
                *(float4*)(out + g0) = ov;
            }
        }
    }
}

extern "C" void kernel_launch(void* const* d_in, const int* in_sizes, int n_in,
                              void* d_out, int out_size, void* d_ws, size_t ws_size,
                              hipStream_t stream) {
    const float* x          = (const float*)d_in[0];
    const float* norm_w     = (const float*)d_in[1];
    const float* norm_b     = (const float*)d_in[2];
    const float* w_in       = (const float*)d_in[3];
    const float* ssm_in_w   = (const float*)d_in[4];
    const float* x_proj_w   = (const float*)d_in[5];
    const float* dt_w       = (const float*)d_in[6];
    const float* dt_b       = (const float*)d_in[7];
    // d_in[8] = A_logs : unused by the reference computation
    const float* Ds         = (const float*)d_in[9];
    const float* out_norm_w = (const float*)d_in[10];
    const float* out_norm_b = (const float*)d_in[11];
    const float* ssm_out_w  = (const float*)d_in[12];
    const float* w_out      = (const float*)d_in[13];

    unsigned short* wb = (unsigned short*)d_ws;
    int prep_n = WTOT2 + CC;
    prep_w<<<dim3((prep_n + NTH - 1) / NTH), dim3(NTH), 0, stream>>>(
        w_in, ssm_in_w, x_proj_w, ssm_out_w, w_out, dt_w, dt_b, Ds, wb);

    mamba_fused<<<dim3(1024), dim3(NTH), 0, stream>>>(
        x, norm_w, norm_b, out_norm_w, out_norm_b, wb, (float*)d_out);
}

// Round 8
// 311.025 us; speedup vs baseline: 1.2100x; 1.2078x over previous
//
#include <hip/hip_runtime.h>
#include <hip/hip_bf16.h>
#include <math.h>

// ChannelMambaBlock fused — Round 8: wave-private pixels, state evicted to d_out scratch
// B=4, C=192, H=128, W=128, K=4, DSTATE=8, DTRANK=12
// Block = 4 waves; EACH WAVE privately owns 16 consecutive-W pixels end-to-end.
// grid = 1024 blocks = exactly 4 blocks/CU. ZERO __syncthreads.
// vs R5-R7 (spilled: ~96 live values vs the 64-VGPR allocation -> ~460MB scratch):
//  * z and silu(x2) (48 VGPRs of persistent packed state) now live in the block's
//    OWN 49KB region of d_out (free until GEMM5 writes it; block-exclusive; exactly
//    2x24576B bf16). Same-wave RAW through L2, fenced once with vmcnt(0).
//  * LN1 no longer holds v[48] in regs: raw bf16 packed to LDS in 8-channel groups,
//    re-read to normalize (R4-proven numerics).
// Peak live state ~50-56 regs -> fits the 64-VGPR file without spill.

#define CC    192
#define HH    128
#define WW    128
#define NK    4
#define DST   8
#define DTR   12
#define NTH   256
#define SP    200         // sX row stride (400B: 16B-aligned rows)
#define SD    112         // sXD row stride (224B: 16B-aligned rows)

typedef __attribute__((ext_vector_type(8))) short bh8;   // 8 bf16 = 4 VGPR
typedef __attribute__((ext_vector_type(4))) float f4;

// bf16 weight segments inside d_ws (ushort elems)
#define OFF_WIN    0
#define OFF_SSMIN  73728        // 384*192
#define OFF_XPROJ  147456
#define OFF_SSMOUT 168960       // + 112*192
#define OFF_WOUT   205824
#define OFF_DTW    242688       // + 192*192  -> B_dt [k][c][32]
#define WTOT2      267264       // + 4*192*32
// f32 Dsum[192] at ushort offset WTOT2

#define MFMA(va, vb, vc) __builtin_amdgcn_mfma_f32_16x16x32_bf16(va, vb, vc, 0, 0, 0)

__device__ __forceinline__ float bf2f(unsigned short u) {
    union { unsigned int i; float f; } v; v.i = ((unsigned int)u) << 16; return v.f;
}
__device__ __forceinline__ unsigned short f2bf(float f) {
    __hip_bfloat16 h = __float2bfloat16(f);
    unsigned short u; __builtin_memcpy(&u, &h, 2); return u;
}
__device__ __forceinline__ unsigned int pk2(float a, float b) {
    return (unsigned int)f2bf(a) | ((unsigned int)f2bf(b) << 16);
}
__device__ __forceinline__ float lo16(unsigned int u) { return bf2f((unsigned short)(u & 0xffffu)); }
__device__ __forceinline__ float hi16(unsigned int u) { return bf2f((unsigned short)(u >> 16)); }

#define LOG2E 1.44269504f
#define LN2C  0.69314718f
__device__ __forceinline__ float silu_fast(float x) {
    float e = __builtin_amdgcn_exp2f(-LOG2E * x);
    return x * __builtin_amdgcn_rcpf(1.f + e);
}
__device__ __forceinline__ float softplus_fast(float x) {
    float e = __builtin_amdgcn_exp2f(-LOG2E * fabsf(x));
    return fmaxf(x, 0.f) + LN2C * __builtin_amdgcn_logf(1.f + e);
}

extern "C" __global__ void prep_w(const float* __restrict__ w_in,
                                  const float* __restrict__ ssm_in_w,
                                  const float* __restrict__ x_proj_w,
                                  const float* __restrict__ ssm_out_w,
                                  const float* __restrict__ w_out,
                                  const float* __restrict__ dt_w,
                                  const float* __restrict__ dt_b,
                                  const float* __restrict__ Ds,
                                  unsigned short* __restrict__ wb)
{
    int i = blockIdx.x * NTH + threadIdx.x;
    if (i < OFF_DTW) {
        float v;
        if      (i < OFF_XPROJ ) v = (i < OFF_SSMIN) ? w_in[i] : ssm_in_w[i - OFF_SSMIN];
        else if (i < OFF_SSMOUT) v = x_proj_w[i - OFF_XPROJ];
        else if (i < OFF_WOUT  ) v = ssm_out_w[i - OFF_SSMOUT];
        else                     v = w_out[i - OFF_WOUT];
        wb[i] = f2bf(v);
    } else if (i < WTOT2) {
        int j  = i - OFF_DTW;
        int r  = j & 31;
        int kc = j >> 5;
        float v = (r < DTR) ? dt_w[kc * DTR + r]
                            : (r == 31 ? dt_b[kc] : 0.f);
        wb[i] = f2bf(v);
    } else if (i < WTOT2 + CC) {
        int c = i - WTOT2;
        float* dsum = (float*)(wb + WTOT2);
        dsum[c] = Ds[c] + Ds[CC + c] + Ds[2*CC + c] + Ds[3*CC + c];
    }
}

template<int NT>
__device__ __forceinline__ void gemmN(const bh8 a[6], const unsigned short* wp,
                                      f4 acc[NT]) {
#pragma unroll
    for (int ks = 0; ks < 6; ++ks)
#pragma unroll
        for (int j = 0; j < NT; ++j) {
            bh8 bf = *(const bh8*)(wp + (size_t)j * 16 * CC + ks * 32);
            acc[j] = MFMA(a[ks], bf, acc[j]);
        }
}

extern "C" __global__ void __launch_bounds__(NTH, 4)
mamba_fused(const float* __restrict__ x,
            const float* __restrict__ norm_w,  const float* __restrict__ norm_b,
            const float* __restrict__ out_norm_w, const float* __restrict__ out_norm_b,
            const unsigned short* __restrict__ wsb,
            float* __restrict__ out)
{
    __shared__ __align__(16) unsigned short sX [4][16][SP];   // 25600 B
    __shared__ __align__(16) unsigned short sXD[4][16][SD];   // 14336 B
    __shared__ __align__(16) float sbc[4][NK][16];            //  1024 B => 40960 B

    const int tid  = threadIdx.x;
    const int lane = tid & 63;
    const int wv   = tid >> 6;
    const int frow = lane & 15;
    const int kb   = lane >> 4;
    const int pxb  = kb * 4;

    const int t   = blockIdx.x;          // 1024 blocks
    const int b   = t >> 8;
    const int rem = t & 255;
    const int h   = rem >> 1;
    const int wbase = (rem & 1) * 64;           // block's 64-pixel base
    const int w0  = wbase + wv * 16;            // wave's first pixel (w coord)

    unsigned short (*mX)[SP]  = sX[wv];
    unsigned short (*mXD)[SD] = sXD[wv];
    float (*mbc)[16]          = sbc[wv];

    const float* dsum = (const float*)(wsb + WTOT2);

    // ---- bf16 scratch mapped onto the block's OWN out region (free until GEMM5).
    // unit u (8B), u in [0,6144): cid = u>>5 (channel plane), (u&31)*2 floats in.
    // z:  u = wv*768 + tile*64 + lane         (tile 0..11)
    // x2: u = 3072 + wv*768 + tile*64 + lane
    auto scr = [&](int u) -> uint2* {
        int cid = u >> 5;
        size_t f = (((size_t)b * CC + cid) * HH + h) * WW + wbase + ((u & 31) << 1);
        return (uint2*)(out + f);
    };
    const int ubase = wv * 768 + lane;

    // ---------------- LN1: load x -> raw bf16 in mX, stats on the fly -----------
    {
        const int c0 = kb * 48;
        const size_t base = (((size_t)b * CC + c0) * HH + h) * WW + w0 + frow;
        float sum = 0.f, sq = 0.f;
#pragma unroll
        for (int gg = 0; gg < 6; ++gg) {
            float v0 = x[base + (size_t)(gg*8+0) * (HH*WW)];
            float v1 = x[base + (size_t)(gg*8+1) * (HH*WW)];
            float v2 = x[base + (size_t)(gg*8+2) * (HH*WW)];
            float v3 = x[base + (size_t)(gg*8+3) * (HH*WW)];
            float v4 = x[base + (size_t)(gg*8+4) * (HH*WW)];
            float v5 = x[base + (size_t)(gg*8+5) * (HH*WW)];
            float v6 = x[base + (size_t)(gg*8+6) * (HH*WW)];
            float v7 = x[base + (size_t)(gg*8+7) * (HH*WW)];
            sum += v0+v1+v2+v3+v4+v5+v6+v7;
            sq  += v0*v0+v1*v1+v2*v2+v3*v3+v4*v4+v5*v5+v6*v6+v7*v7;
            uint4 pkd;
            pkd.x = pk2(v0, v1); pkd.y = pk2(v2, v3);
            pkd.z = pk2(v4, v5); pkd.w = pk2(v6, v7);
            *(uint4*)(&mX[frow][c0 + gg*8]) = pkd;
        }
        sum += __shfl_xor(sum, 16); sum += __shfl_xor(sum, 32);
        sq  += __shfl_xor(sq , 16); sq  += __shfl_xor(sq , 32);
        float mu = sum * (1.f / CC);
        float rs = rsqrtf(sq * (1.f / CC) - mu * mu + 1e-5f);
#pragma unroll
        for (int gg = 0; gg < 6; ++gg) {
            int c = c0 + gg*8;
            uint4 pkd = *(const uint4*)(&mX[frow][c]);
            uint4 o;
            o.x = pk2((lo16(pkd.x)-mu)*rs*norm_w[c+0]+norm_b[c+0],
                      (hi16(pkd.x)-mu)*rs*norm_w[c+1]+norm_b[c+1]);
            o.y = pk2((lo16(pkd.y)-mu)*rs*norm_w[c+2]+norm_b[c+2],
                      (hi16(pkd.y)-mu)*rs*norm_w[c+3]+norm_b[c+3]);
            o.z = pk2((lo16(pkd.z)-mu)*rs*norm_w[c+4]+norm_b[c+4],
                      (hi16(pkd.z)-mu)*rs*norm_w[c+5]+norm_b[c+5]);
            o.w = pk2((lo16(pkd.w)-mu)*rs*norm_w[c+6]+norm_b[c+6],
                      (hi16(pkd.w)-mu)*rs*norm_w[c+7]+norm_b[c+7]);
            *(uint4*)(&mX[frow][c]) = o;
        }
    }

    bh8 a[6];
    auto load_a = [&]() {
#pragma unroll
        for (int ks = 0; ks < 6; ++ks)
            a[ks] = *(const bh8*)(&mX[frow][ks * 32 + kb * 8]);
    };

    // ---------------- GEMM1: p = xn @ w_in^T -> mX = x1, scratch = silu(x2) -----
    {
        load_a();
        const unsigned short* wB = wsb + OFF_WIN;
#pragma unroll
        for (int g = 0; g < 6; ++g) {
            f4 acc[4] = {{0,0,0,0},{0,0,0,0},{0,0,0,0},{0,0,0,0}};
            gemmN<4>(a, wB + (size_t)(g * 64 + frow) * CC + kb * 8, acc);
#pragma unroll
            for (int j = 0; j < 4; ++j) {
                int tile = g * 4 + j;
                int o = tile * 16 + frow;
                if (tile < 12) {
#pragma unroll
                    for (int r = 0; r < 4; ++r) mX[pxb + r][o] = f2bf(acc[j][r]);
                } else {
                    uint2 pv;
                    pv.x = pk2(silu_fast(acc[j][0]), silu_fast(acc[j][1]));
                    pv.y = pk2(silu_fast(acc[j][2]), silu_fast(acc[j][3]));
                    *scr(3072 + ubase + (tile - 12) * 64) = pv;
                }
            }
        }
    }

    // ---------------- GEMM2: u = x1 @ ssm_in^T -> mX = silu(xss), scratch = z ---
    {
        load_a();                       // x1
        const unsigned short* wB = wsb + OFF_SSMIN;
#pragma unroll
        for (int g = 0; g < 6; ++g) {
            f4 acc[4] = {{0,0,0,0},{0,0,0,0},{0,0,0,0},{0,0,0,0}};
            gemmN<4>(a, wB + (size_t)(g * 64 + frow) * CC + kb * 8, acc);
#pragma unroll
            for (int j = 0; j < 4; ++j) {
                int tile = g * 4 + j;
                int o = tile * 16 + frow;
                if (tile < 12) {
#pragma unroll
                    for (int r = 0; r < 4; ++r)
                        mX[pxb + r][o] = f2bf(silu_fast(acc[j][r]));
                } else {
                    uint2 pv;
                    pv.x = pk2(silu_fast(acc[j][0]), silu_fast(acc[j][1]));
                    pv.y = pk2(silu_fast(acc[j][2]), silu_fast(acc[j][3]));
                    *scr(ubase + (tile - 12) * 64) = pv;
                }
            }
        }
    }

    // ---------------- GEMM3: xd = xss @ x_proj^T (112) -> mXD -------------------
    {
        load_a();                       // silu(xss)
        const unsigned short* wB = wsb + OFF_XPROJ;
        {
            f4 acc[4] = {{0,0,0,0},{0,0,0,0},{0,0,0,0},{0,0,0,0}};
            gemmN<4>(a, wB + (size_t)frow * CC + kb * 8, acc);
#pragma unroll
            for (int j = 0; j < 4; ++j) {
                int o = j * 16 + frow;
#pragma unroll
                for (int r = 0; r < 4; ++r) mXD[pxb + r][o] = f2bf(acc[j][r]);
            }
        }
        {
            f4 acc[3] = {{0,0,0,0},{0,0,0,0},{0,0,0,0}};
            gemmN<3>(a, wB + (size_t)(64 + frow) * CC + kb * 8, acc);
#pragma unroll
            for (int j = 0; j < 3; ++j) {
                int o = (4 + j) * 16 + frow;
#pragma unroll
                for (int r = 0; r < 4; ++r) mXD[pxb + r][o] = f2bf(acc[j][r]);
            }
        }
    }

    // ---------------- bc[k][px] = dot(Bv, Cv) -----------------------------------
    {
        const unsigned short* rp = &mXD[frow][kb * 28 + DTR];
        float acc = 0.f;
#pragma unroll
        for (int s = 0; s < DST; ++s)
            acc += bf2f(rp[s]) * bf2f(rp[DST + s]);
        mbc[kb][frow] = acc;
    }

    // ---------------- dt-MFMA: y = xss*(sum_k bc*softplus(.) + Dsum) ------------
    // y written IN-PLACE into mX; LN2 stats accumulated on the fly.
    f4 l2sum = {0.f,0.f,0.f,0.f}, l2sq = {0.f,0.f,0.f,0.f};
    {
        bh8 adt[NK];
#pragma unroll
        for (int k = 0; k < NK; ++k) {
            const unsigned short* rp = &mXD[frow][k * 28];
            bh8 vv;
            if (kb == 0) {
                ushort4 lo = *(const ushort4*)(rp);
                ushort4 hi = *(const ushort4*)(rp + 4);
                vv = bh8{(short)lo.x,(short)lo.y,(short)lo.z,(short)lo.w,
                         (short)hi.x,(short)hi.y,(short)hi.z,(short)hi.w};
            } else if (kb == 1) {
                ushort4 lo = *(const ushort4*)(rp + 8);
                vv = bh8{(short)lo.x,(short)lo.y,(short)lo.z,(short)lo.w,0,0,0,0};
            } else if (kb == 2) {
                vv = bh8{0,0,0,0,0,0,0,0};
            } else {
                vv = bh8{0,0,0,0,0,0,0,(short)0x3F80};   // bf16 1.0 -> col 31 (dt_b)
            }
            adt[k] = vv;
        }
        f4 bck[NK];
#pragma unroll
        for (int k = 0; k < NK; ++k) bck[k] = *(const f4*)(&mbc[k][pxb]);

        const unsigned short* wDT = wsb + OFF_DTW;
#pragma unroll
        for (int ct = 0; ct < 12; ++ct) {
            int c = ct * 16 + frow;
            f4 g = {0.f,0.f,0.f,0.f};
#pragma unroll
            for (int k = 0; k < NK; ++k) {
                bh8 bf = *(const bh8*)(wDT + (((size_t)(k * CC + c)) << 5) + kb * 8);
                f4 d = {0.f,0.f,0.f,0.f};
                d = MFMA(adt[k], bf, d);
#pragma unroll
                for (int r = 0; r < 4; ++r)
                    g[r] += bck[k][r] * softplus_fast(d[r]);
            }
            float ds = dsum[c];
#pragma unroll
            for (int r = 0; r < 4; ++r) {
                float yv = bf2f(mX[pxb + r][c]) * (g[r] + ds);
                mX[pxb + r][c] = f2bf(yv);            // in-place: xss slot -> y
                l2sum[r] += yv; l2sq[r] += yv * yv;
            }
        }
    }

    // ---- fence: all scratch stores (z, x2) retired to L2 before first re-read --
    asm volatile("s_waitcnt vmcnt(0)" ::: "memory");

    // ---------------- LN2 over y (per pixel), * z(scratch) -> mX = yz -----------
    {
#pragma unroll
        for (int m = 1; m < 16; m <<= 1) {
#pragma unroll
            for (int r = 0; r < 4; ++r) {
                l2sum[r] += __shfl_xor(l2sum[r], m);
                l2sq[r]  += __shfl_xor(l2sq[r],  m);
            }
        }
        f4 mu, rs;
#pragma unroll
        for (int r = 0; r < 4; ++r) {
            mu[r] = l2sum[r] * (1.f / CC);
            rs[r] = rsqrtf(l2sq[r] * (1.f / CC) - mu[r] * mu[r] + 1e-5f);
        }
#pragma unroll
        for (int ct = 0; ct < 12; ++ct) {
            int c = ct * 16 + frow;
            uint2 zv = *scr(ubase + ct * 64);
            float wn = out_norm_w[c], bn = out_norm_b[c];
            float y0 = bf2f(mX[pxb + 0][c]);
            float y1 = bf2f(mX[pxb + 1][c]);
            float y2 = bf2f(mX[pxb + 2][c]);
            float y3 = bf2f(mX[pxb + 3][c]);
            mX[pxb + 0][c] = f2bf(((y0 - mu[0]) * rs[0] * wn + bn) * lo16(zv.x));
            mX[pxb + 1][c] = f2bf(((y1 - mu[1]) * rs[1] * wn + bn) * hi16(zv.x));
            mX[pxb + 2][c] = f2bf(((y2 - mu[2]) * rs[2] * wn + bn) * lo16(zv.y));
            mX[pxb + 3][c] = f2bf(((y3 - mu[3]) * rs[3] * wn + bn) * hi16(zv.y));
        }
    }

    // ---------------- GEMM4: s = yz @ ssm_out^T; mX = s * silu(x2)(scratch) -----
    {
        load_a();                       // yz
        const unsigned short* wB = wsb + OFF_SSMOUT;
#pragma unroll
        for (int g = 0; g < 3; ++g) {
            f4 acc[4] = {{0,0,0,0},{0,0,0,0},{0,0,0,0},{0,0,0,0}};
            gemmN<4>(a, wB + (size_t)(g * 64 + frow) * CC + kb * 8, acc);
            uint2 x2v0 = *scr(3072 + ubase + (g*4 + 0) * 64);
            uint2 x2v1 = *scr(3072 + ubase + (g*4 + 1) * 64);
            uint2 x2v2 = *scr(3072 + ubase + (g*4 + 2) * 64);
            uint2 x2v3 = *scr(3072 + ubase + (g*4 + 3) * 64);
            int o0 = (g*4) * 16 + frow;
            mX[pxb + 0][o0     ] = f2bf(acc[0][0] * lo16(x2v0.x));
            mX[pxb + 1][o0     ] = f2bf(acc[0][1] * hi16(x2v0.x));
            mX[pxb + 2][o0     ] = f2bf(acc[0][2] * lo16(x2v0.y));
            mX[pxb + 3][o0     ] = f2bf(acc[0][3] * hi16(x2v0.y));
            mX[pxb + 0][o0 + 16] = f2bf(acc[1][0] * lo16(x2v1.x));
            mX[pxb + 1][o0 + 16] = f2bf(acc[1][1] * hi16(x2v1.x));
            mX[pxb + 2][o0 + 16] = f2bf(acc[1][2] * lo16(x2v1.y));
            mX[pxb + 3][o0 + 16] = f2bf(acc[1][3] * hi16(x2v1.y));
            mX[pxb + 0][o0 + 32] = f2bf(acc[2][0] * lo16(x2v2.x));
            mX[pxb + 1][o0 + 32] = f2bf(acc[2][1] * hi16(x2v2.x));
            mX[pxb + 2][o0 + 32] = f2bf(acc[2][2] * lo16(x2v2.y));
            mX[pxb + 3][o0 + 32] = f2bf(acc[2][3] * hi16(x2v2.y));
            mX[pxb + 0][o0 + 48] = f2bf(acc[3][0] * lo16(x2v3.x));
            mX[pxb + 1][o0 + 48] = f2bf(acc[3][1] * hi16(x2v3.x));
            mX[pxb + 2][o0 + 48] = f2bf(acc[3][2] * lo16(x2v3.y));
            mX[pxb + 3][o0 + 48] = f2bf(acc[3][3] * hi16(x2v3.y));
        }
    }

    // ---------------- GEMM5: o = (s*x2) @ w_out^T; out = x + o ------------------
    // (all scratch reads above completed in-wave before these stores)
    {
        load_a();                       // s*x2
        const unsigned short* wB = wsb + OFF_WOUT;
#pragma unroll
        for (int g = 0; g < 3; ++g) {
            f4 acc[4] = {{0,0,0,0},{0,0,0,0},{0,0,0,0},{0,0,0,0}};
            gemmN<4>(a, wB + (size_t)(g * 64 + frow) * CC + kb * 8, acc);
#pragma unroll
            for (int j = 0; j < 4; ++j) {
                int o = (g * 4 + j) * 16 + frow;
                const size_t g0 = (((size_t)b * CC + o) * HH + h) * WW + w0 + pxb;
                float4 xv = *(const float4*)(x + g0);
                float4 ov;
                ov.x = xv.x + acc[j][0];
                ov.y = xv.y + acc[j][1];
                ov.z = xv.z + acc[j][2];
                ov.w = xv.w + acc[j][3];
                *(float4*)(out + g0) = ov;
            }
        }
    }
}

extern "C" void kernel_launch(void* const* d_in, const int* in_sizes, int n_in,
                              void* d_out, int out_size, void* d_ws, size_t ws_size,
                              hipStream_t stream) {
    const float* x          = (const float*)d_in[0];
    const float* norm_w     = (const float*)d_in[1];
    const float* norm_b     = (const float*)d_in[2];
    const float* w_in       = (const float*)d_in[3];
    const float* ssm_in_w   = (const float*)d_in[4];
    const float* x_proj_w   = (const float*)d_in[5];
    const float* dt_w       = (const float*)d_in[6];
    const float* dt_b       = (const float*)d_in[7];
    // d_in[8] = A_logs : unused by the reference computation
    const float* Ds         = (const float*)d_in[9];
    const float* out_norm_w = (const float*)d_in[10];
    const float* out_norm_b = (const float*)d_in[11];
    const float* ssm_out_w  = (const float*)d_in[12];
    const float* w_out      = (const float*)d_in[13];

    unsigned short* wb = (unsigned short*)d_ws;
    int prep_n = WTOT2 + CC;
    prep_w<<<dim3((prep_n + NTH - 1) / NTH), dim3(NTH), 0, stream>>>(
        w_in, ssm_in_w, x_proj_w, ssm_out_w, w_out, dt_w, dt_b, Ds, wb);

    mamba_fused<<<dim3(1024), dim3(NTH), 0, stream>>>(
        x, norm_w, norm_b, out_norm_w, out_norm_b, wb, (float*)d_out);
}